// Round 8
// baseline (386.508 us; speedup 1.0000x reference)
//
#include <hip/hip_runtime.h>

#define N_NODES 50000
#define N_EDGES 800000
#define DIM     128
#define NGRAPH  128
#define NCLASS  10
#define NLAYER  4

#define TEAMS   256
#define ESLICE  (N_EDGES / TEAMS)    // 3125 edges per team slice
#define CWORDS  12500                // 50000 nodes / 4 (byte per node, word-packed)

typedef __attribute__((ext_vector_type(8))) short short8;
typedef __attribute__((ext_vector_type(4))) float floatx4;

__device__ __forceinline__ unsigned f2bf(float f) {
    union { float f; unsigned u; } v; v.f = f;
    return (v.u + 0x7fffu + ((v.u >> 16) & 1u)) >> 16;   // RNE
}
__device__ __forceinline__ float bf_lo(unsigned u) { return __uint_as_float(u << 16); }
__device__ __forceinline__ float bf_hi(unsigned u) { return __uint_as_float(u & 0xffff0000u); }

// ---------------------------------------------------------------------------
// Blocks 0..255: per-team-slice nibble histograms (in=low nibble, out=high).
// Blocks 256..263: W pre-swizzle into MFMA B-fragment order (bf16).
__global__ __launch_bounds__(1024) void count_wprep_kernel(
    const int* __restrict__ ei, unsigned* __restrict__ cntw,
    const float* __restrict__ W0, const float* __restrict__ Ws,
    uint4* __restrict__ Wf)
{
    int tid = threadIdx.x;
    if (blockIdx.x >= TEAMS) {
        int t = (blockIdx.x - TEAMS) * 1024 + tid;
        if (t < NLAYER * 2048) {
            int layer = t >> 11;
            int rem = t & 2047;
            int lane = rem & 63;
            int s = (rem >> 6) & 3;
            int c = rem >> 8;
            int quad = lane >> 4, colw = c * 16 + (lane & 15);
            int k0 = s * 32 + quad * 8;
            const float* W = (layer == 0) ? W0 : Ws + (size_t)(layer - 1) * DIM * DIM;
            uint4 p;
            unsigned* pp = (unsigned*)&p;
#pragma unroll
            for (int j = 0; j < 4; ++j) {
                unsigned lo = f2bf(W[(size_t)(k0 + 2 * j) * DIM + colw]);
                unsigned hi = f2bf(W[(size_t)(k0 + 2 * j + 1) * DIM + colw]);
                pp[j] = lo | (hi << 16);
            }
            Wf[t] = p;
        }
        return;
    }
    __shared__ unsigned h[CWORDS];      // 50 KB
    int team = blockIdx.x;
    for (int i = tid; i < CWORDS; i += 1024) h[i] = 0;
    __syncthreads();
    const int e0 = team * ESLICE;
    const int* __restrict__ srcp = ei;
    const int* __restrict__ dstp = ei + N_EDGES;
    for (int e = e0 + tid; e < e0 + ESLICE; e += 1024) {
        int s = srcp[e], d = dstp[e];
        atomicAdd(&h[d >> 2], 1u  << (8 * (d & 3)));   // in-count  (low nibble)
        atomicAdd(&h[s >> 2], 16u << (8 * (s & 3)));   // out-count (high nibble)
    }
    __syncthreads();
    for (int i = tid; i < CWORDS; i += 1024)
        cntw[(size_t)team * CWORDS + i] = h[i];
}

// Per-node exclusive prefix over 256 team counts -> byte slot offsets;
// totals -> cnt_dense, c_src, c_dst; then prescale hs = x*c_src for the tile.
// Thread layout for the scan: tid = nl*4 + q (nl=node-local 0..255, q=quarter),
// each thread scans 32 teams/phase; width-4 shfl prefix combines quarters.
__global__ __launch_bounds__(1024) void offsets_prescale_kernel(
    const unsigned* __restrict__ cntw, unsigned* __restrict__ offsw,
    unsigned* __restrict__ cnt_dense, float* __restrict__ c_src,
    float* __restrict__ c_dst, const float2* __restrict__ x,
    unsigned* __restrict__ hs)
{
    __shared__ unsigned ldsC[128 * 64];   // counts tile [teamLocal][word]  32KB
    __shared__ unsigned ldsO[128 * 64];   // offset bytes [teamLocal][node] 32KB
    int tid = threadIdx.x;
    int n0 = blockIdx.x * 256;
    int w0 = n0 >> 2;
    int nl = tid >> 2;          // node-local 0..255
    int qq = tid & 3;           // quarter 0..3
    int myw = nl >> 2, myb = 8 * (nl & 3);
    unsigned carry = 0;         // full in-prefix for node nl (all threads agree)
    unsigned od_part = 0;       // per-thread out-degree partial

    for (int ph = 0; ph < 2; ++ph) {
        int t0 = ph * 128;
        for (int i = tid; i < 128 * 64; i += 1024) {
            int tl = i >> 6, wl = i & 63;
            int gw = w0 + wl;
            ldsC[i] = (gw < CWORDS) ? cntw[(size_t)(t0 + tl) * CWORDS + gw] : 0u;
        }
        __syncthreads();
        // local scan of my 32 teams
        unsigned lin = 0;
        unsigned char* ob = (unsigned char*)ldsO;
        int tl0 = qq * 32;
        for (int i = 0; i < 32; ++i) {
            int tl = tl0 + i;
            unsigned b = (ldsC[tl * 64 + myw] >> myb) & 255u;
            ob[tl * 256 + nl] = (unsigned char)lin;
            lin += (b & 15u);
            od_part += (b >> 4);
        }
        // combine quarters: exclusive prefix of lin over q
        unsigned v1 = __shfl_up(lin, 1, 4);
        unsigned v2 = __shfl_up(lin, 2, 4);
        unsigned v3 = __shfl_up(lin, 3, 4);
        unsigned ein = (qq >= 1 ? v1 : 0u) + (qq >= 2 ? v2 : 0u) + (qq >= 3 ? v3 : 0u);
        unsigned base = carry + ein;
        for (int i = 0; i < 32; ++i) {
            int tl = tl0 + i;
            ob[tl * 256 + nl] = (unsigned char)(ob[tl * 256 + nl] + base);
        }
        carry += __shfl(ein + lin, 3, 4);   // phase total (q=3 inclusive)
        __syncthreads();
        for (int i = tid; i < 128 * 64; i += 1024) {
            int tl = i >> 6, wl = i & 63;
            int gw = w0 + wl;
            if (gw < CWORDS) offsw[(size_t)(t0 + tl) * CWORDS + gw] = ldsO[i];
        }
        __syncthreads();
    }
    // degrees -> norms; stage c_src in LDS (reuse ldsC) for prescale
    float* ldsCs = (float*)ldsC;
    unsigned od = od_part;
    od += __shfl_xor(od, 1, 4);
    od += __shfl_xor(od, 2, 4);
    if (qq == 0) {
        int n = n0 + nl;
        unsigned id_ = carry;
        float cs;
        {
            unsigned idc = id_ < 1u ? 1u : id_;
            unsigned odc = od < 1u ? 1u : od;
            cs = 1.0f / sqrtf((float)odc);
            if (n < N_NODES) {
                cnt_dense[n] = id_ > 64u ? 64u : id_;
                c_dst[n] = 1.0f / sqrtf((float)idc);
                c_src[n] = cs;
            }
        }
        ldsCs[nl] = cs;
    }
    __syncthreads();
    // prescale this tile's 256 rows: hs = bf16(x * c_src)
    for (int i = tid; i < 256 * 64; i += 1024) {
        int row = i >> 6, col = i & 63;
        int n = n0 + row;
        if (n >= N_NODES) break;
        float c = ldsCs[row];
        float2 v = x[(size_t)n * 64 + col];
        hs[(size_t)n * 64 + col] = f2bf(v.x * c) | (f2bf(v.y * c) << 16);
    }
}

// Rescan slice, LDS position counters give unique local pos; write src
// directly into dense CSR at offs(team,d)+pos.
__global__ __launch_bounds__(1024) void scatter_kernel(
    const int* __restrict__ ei, const unsigned* __restrict__ offsw,
    unsigned* __restrict__ colc)
{
    __shared__ unsigned h[CWORDS];      // 50 KB pos counters (low nibble)
    int team = blockIdx.x, tid = threadIdx.x;
    for (int i = tid; i < CWORDS; i += 1024) h[i] = 0;
    __syncthreads();
    const unsigned char* __restrict__ ob =
        (const unsigned char*)offsw + (size_t)team * 50000;
    const int e0 = team * ESLICE;
    const int* __restrict__ srcp = ei;
    const int* __restrict__ dstp = ei + N_EDGES;
    for (int e = e0 + tid; e < e0 + ESLICE; e += 1024) {
        int s = srcp[e], d = dstp[e];
        unsigned old = atomicAdd(&h[d >> 2], 1u << (8 * (d & 3)));
        unsigned pos = (old >> (8 * (d & 3))) & 15u;
        unsigned slot = (unsigned)ob[d] + pos;
        if (slot < 64u) colc[(size_t)d * 64 + slot] = (unsigned)s;
    }
}

// m[n] = sum over in-edges of hs[src]. One wave per node; four 16-lane groups
// gather FOUR different edges' rows per uint4 load (1 KB per instruction).
__global__ __launch_bounds__(256) void aggregate_kernel(
    const unsigned* __restrict__ hs, const unsigned* __restrict__ colc,
    const unsigned* __restrict__ cnt_dense, unsigned* __restrict__ m,
    int total_waves)
{
    int wid  = (blockIdx.x * blockDim.x + threadIdx.x) >> 6;
    int lane = threadIdx.x & 63;
    int g = lane >> 4;             // edge-group 0..3
    int t = lane & 15;             // 16B chunk within row: uints 4t..4t+3
    for (int n = wid; n < N_NODES; n += total_waves) {
        unsigned deg = cnt_dense[n];
        unsigned myidx = colc[(size_t)n * 64 + lane];   // coalesced 256B
        float f0 = 0.f, f1 = 0.f, f2 = 0.f, f3 = 0.f;
        float f4 = 0.f, f5 = 0.f, f6 = 0.f, f7 = 0.f;
        for (unsigned j = 0; j < deg; j += 4) {
            unsigned e = j + g;
            unsigned s = (unsigned)__shfl((int)myidx, (int)e);
            bool v = e < deg;
            s = v ? s : 0u;
            uint4 u = *(const uint4*)(hs + (size_t)s * 64 + t * 4);
            if (!v) { u.x = 0u; u.y = 0u; u.z = 0u; u.w = 0u; }
            f0 += bf_lo(u.x); f1 += bf_hi(u.x);
            f2 += bf_lo(u.y); f3 += bf_hi(u.y);
            f4 += bf_lo(u.z); f5 += bf_hi(u.z);
            f6 += bf_lo(u.w); f7 += bf_hi(u.w);
        }
        f0 += __shfl_xor(f0, 16); f1 += __shfl_xor(f1, 16);
        f2 += __shfl_xor(f2, 16); f3 += __shfl_xor(f3, 16);
        f4 += __shfl_xor(f4, 16); f5 += __shfl_xor(f5, 16);
        f6 += __shfl_xor(f6, 16); f7 += __shfl_xor(f7, 16);
        f0 += __shfl_xor(f0, 32); f1 += __shfl_xor(f1, 32);
        f2 += __shfl_xor(f2, 32); f3 += __shfl_xor(f3, 32);
        f4 += __shfl_xor(f4, 32); f5 += __shfl_xor(f5, 32);
        f6 += __shfl_xor(f6, 32); f7 += __shfl_xor(f7, 32);
        if (g == 0) {
            uint4 r;
            r.x = f2bf(f0) | (f2bf(f1) << 16);
            r.y = f2bf(f2) | (f2bf(f3) << 16);
            r.z = f2bf(f4) | (f2bf(f5) << 16);
            r.w = f2bf(f6) | (f2bf(f7) << 16);
            *(uint4*)(m + (size_t)n * 64 + t * 4) = r;
        }
    }
}

// Hout = relu(c_dst[r]*(M@W) + b) [* c_src[r] if !last], MFMA 16x16x32 bf16.
__global__ __launch_bounds__(256) void mfma_gemm_kernel(
    const uint4* __restrict__ Mb, const uint4* __restrict__ Wf,
    const float* __restrict__ bias, const float* __restrict__ c_dst,
    const float* __restrict__ c_src, unsigned short* __restrict__ out_bf,
    float* __restrict__ out_f32, int last)
{
    int tid = threadIdx.x;
    int wave = tid >> 6, lane = tid & 63;
    int quad = lane >> 4, m16 = lane & 15;
    int r0 = blockIdx.x * 64 + wave * 16;

    int rA = r0 + m16; if (rA >= N_NODES) rA = N_NODES - 1;
    const uint4* pA = Mb + (size_t)rA * 16 + quad;
    union U { uint4 u; short8 s; };
    U a[4];
#pragma unroll
    for (int s = 0; s < 4; ++s) a[s].u = pA[s * 4];

    floatx4 acc[8];
#pragma unroll
    for (int c = 0; c < 8; ++c) {
        floatx4 ac = {0.f, 0.f, 0.f, 0.f};
#pragma unroll
        for (int s = 0; s < 4; ++s) {
            U b; b.u = Wf[(c * 4 + s) * 64 + lane];
            ac = __builtin_amdgcn_mfma_f32_16x16x32_bf16(a[s].s, b.s, ac, 0, 0, 0);
        }
        acc[c] = ac;
    }

    float cd[4], cs[4];
    int rows[4];
#pragma unroll
    for (int r = 0; r < 4; ++r) {
        int row = r0 + quad * 4 + r; rows[r] = row;
        bool ok = row < N_NODES;
        cd[r] = ok ? c_dst[row] : 0.f;
        cs[r] = (ok && !last) ? c_src[row] : 1.f;
    }
#pragma unroll
    for (int c = 0; c < 8; ++c) {
        int colg = c * 16 + m16;
        float b = bias[colg];
#pragma unroll
        for (int r = 0; r < 4; ++r) {
            int row = rows[r];
            if (row >= N_NODES) continue;
            float v = acc[c][r] * cd[r] + b;
            v = v > 0.f ? v : 0.f;
            if (last) out_f32[(size_t)row * DIM + colg] = v;
            else      out_bf[(size_t)row * DIM + colg] = (unsigned short)f2bf(v * cs[r]);
        }
    }
}

// Fused mean-pool readout + linear head. One block per graph; gid sorted so
// the graph's nodes are a contiguous range found by binary search. No atomics.
__global__ __launch_bounds__(256) void readout_head_kernel(
    const float* __restrict__ h, const int* __restrict__ gid,
    const float* __restrict__ Wc, const float* __restrict__ bc,
    float* __restrict__ out)
{
    __shared__ float sv[256];
    int g = blockIdx.x;
    int tid = threadIdx.x;
    // lower_bound(gid, g) and lower_bound(gid, g+1), computed by all threads
    int lo = 0, hi = N_NODES;
    while (lo < hi) { int mid = (lo + hi) >> 1; if (gid[mid] < g) lo = mid + 1; else hi = mid; }
    int lo2 = lo, hi2 = N_NODES;
    while (lo2 < hi2) { int mid = (lo2 + hi2) >> 1; if (gid[mid] < g + 1) lo2 = mid + 1; else hi2 = mid; }
    int j = tid & 127, half = tid >> 7;
    float acc = 0.f;
    for (int n = lo + half; n < lo2; n += 2) acc += h[(size_t)n * DIM + j];
    sv[tid] = acc;
    __syncthreads();
    int cnt = lo2 - lo;
    float inv = 1.0f / (float)(cnt < 1 ? 1 : cnt);
    float hgj = (sv[j] + sv[j + 128]) * inv;
    __syncthreads();
    if (tid < 128) sv[j] = hgj;
    __syncthreads();
    if (tid < NCLASS) {
        float s = bc[tid];
        for (int j2 = 0; j2 < DIM; ++j2) s = fmaf(sv[j2], Wc[j2 * NCLASS + tid], s);
        out[g * NCLASS + tid] = s;
    }
}

// ---------------------------------------------------------------------------
extern "C" void kernel_launch(void* const* d_in, const int* in_sizes, int n_in,
                              void* d_out, int out_size, void* d_ws, size_t ws_size,
                              hipStream_t stream)
{
    const float* x   = (const float*)d_in[0];
    const float* W0  = (const float*)d_in[1];
    const float* b0  = (const float*)d_in[2];
    const float* Ws  = (const float*)d_in[3];
    const float* bs  = (const float*)d_in[4];
    const float* Wc  = (const float*)d_in[5];
    const float* bc  = (const float*)d_in[6];
    const int*   ei  = (const int*)d_in[7];
    const int*   gid = (const int*)d_in[8];
    float* out = (float*)d_out;

    char* ws = (char*)d_ws;
    size_t o = 0;
    auto alloc = [&](size_t bytes) {
        size_t r = o; o = (o + bytes + 255) & ~(size_t)255; return r;
    };
    unsigned* cntw      = (unsigned*)(ws + alloc((size_t)TEAMS * CWORDS * 4));
    unsigned* offsw     = (unsigned*)(ws + alloc((size_t)TEAMS * CWORDS * 4));
    unsigned* cnt_dense = (unsigned*)(ws + alloc((size_t)N_NODES * 4));
    float*    c_src     = (float*)(ws + alloc((size_t)N_NODES * 4));
    float*    c_dst     = (float*)(ws + alloc((size_t)N_NODES * 4));
    unsigned* colc      = (unsigned*)(ws + alloc((size_t)N_NODES * 64 * 4));
    unsigned* hs        = (unsigned*)(ws + alloc((size_t)N_NODES * 64 * 4));
    unsigned* mbuf      = (unsigned*)(ws + alloc((size_t)N_NODES * 64 * 4));
    float*    hlast     = (float*)(ws + alloc((size_t)N_NODES * DIM * 4));
    uint4*    Wf        = (uint4*)(ws + alloc((size_t)NLAYER * 2048 * 16));

    count_wprep_kernel<<<TEAMS + 8, 1024, 0, stream>>>(ei, cntw, W0, Ws, Wf);
    offsets_prescale_kernel<<<(N_NODES + 255) / 256, 1024, 0, stream>>>(
        cntw, offsw, cnt_dense, c_src, c_dst, (const float2*)x, hs);
    scatter_kernel<<<TEAMS, 1024, 0, stream>>>(ei, offsw, colc);

    const int AGG_BLOCKS = 2048;
    const int TOTAL_WAVES = AGG_BLOCKS * 4;
    const int GEMM_BLOCKS = (N_NODES + 63) / 64;

    for (int l = 0; l < NLAYER; ++l) {
        const float* b = (l == 0) ? b0 : (bs + (size_t)(l - 1) * DIM);
        int last = (l == NLAYER - 1) ? 1 : 0;
        aggregate_kernel<<<AGG_BLOCKS, 256, 0, stream>>>(
            hs, colc, cnt_dense, mbuf, TOTAL_WAVES);
        mfma_gemm_kernel<<<GEMM_BLOCKS, 256, 0, stream>>>(
            (const uint4*)mbuf, Wf + (size_t)l * 2048, b, c_dst, c_src,
            (unsigned short*)hs, hlast, last);
    }

    readout_head_kernel<<<NGRAPH, 256, 0, stream>>>(hlast, gid, Wc, bc, out);
}

// Round 9
// 352.005 us; speedup vs baseline: 1.0980x; 1.0980x over previous
//
#include <hip/hip_runtime.h>

#define N_NODES 50000
#define N_EDGES 800000
#define DIM     128
#define NGRAPH  128
#define NCLASS  10
#define NLAYER  4

#define TEAMS   256
#define ESLICE  (N_EDGES / TEAMS)    // 3125 edges per team slice
#define CWORDS  12500                // 50000 nodes / 4 (byte per node, word-packed)

typedef __attribute__((ext_vector_type(8))) short short8;
typedef __attribute__((ext_vector_type(4))) float floatx4;

__device__ __forceinline__ unsigned f2bf(float f) {
    union { float f; unsigned u; } v; v.f = f;
    return (v.u + 0x7fffu + ((v.u >> 16) & 1u)) >> 16;   // RNE
}
__device__ __forceinline__ float bf_lo(unsigned u) { return __uint_as_float(u << 16); }
__device__ __forceinline__ float bf_hi(unsigned u) { return __uint_as_float(u & 0xffff0000u); }

// ---------------------------------------------------------------------------
// Blocks 0..255: per-team-slice nibble histograms (in=low nibble, out=high).
// Blocks 256..263: W pre-swizzle into MFMA B-fragment order (bf16).
// Block 264: zero hg / cntg (readout accumulators).
__global__ __launch_bounds__(1024) void count_wprep_kernel(
    const int* __restrict__ ei, unsigned* __restrict__ cntw,
    const float* __restrict__ W0, const float* __restrict__ Ws,
    uint4* __restrict__ Wf, float* __restrict__ hg, float* __restrict__ cntg)
{
    int tid = threadIdx.x;
    if (blockIdx.x >= TEAMS) {
        int xb = blockIdx.x - TEAMS;
        if (xb == 8) {
            for (int i = tid; i < NGRAPH * DIM; i += 1024) hg[i] = 0.f;
            if (tid < NGRAPH) cntg[tid] = 0.f;
            return;
        }
        int t = xb * 1024 + tid;
        if (t < NLAYER * 2048) {
            int layer = t >> 11;
            int rem = t & 2047;
            int lane = rem & 63;
            int s = (rem >> 6) & 3;
            int c = rem >> 8;
            int quad = lane >> 4, colw = c * 16 + (lane & 15);
            int k0 = s * 32 + quad * 8;
            const float* W = (layer == 0) ? W0 : Ws + (size_t)(layer - 1) * DIM * DIM;
            uint4 p;
            unsigned* pp = (unsigned*)&p;
#pragma unroll
            for (int j = 0; j < 4; ++j) {
                unsigned lo = f2bf(W[(size_t)(k0 + 2 * j) * DIM + colw]);
                unsigned hi = f2bf(W[(size_t)(k0 + 2 * j + 1) * DIM + colw]);
                pp[j] = lo | (hi << 16);
            }
            Wf[t] = p;
        }
        return;
    }
    __shared__ unsigned h[CWORDS];      // 50 KB
    int team = blockIdx.x;
    for (int i = tid; i < CWORDS; i += 1024) h[i] = 0;
    __syncthreads();
    const int e0 = team * ESLICE;
    const int* __restrict__ srcp = ei;
    const int* __restrict__ dstp = ei + N_EDGES;
    for (int e = e0 + tid; e < e0 + ESLICE; e += 1024) {
        int s = srcp[e], d = dstp[e];
        atomicAdd(&h[d >> 2], 1u  << (8 * (d & 3)));   // in-count  (low nibble)
        atomicAdd(&h[s >> 2], 16u << (8 * (s & 3)));   // out-count (high nibble)
    }
    __syncthreads();
    for (int i = tid; i < CWORDS; i += 1024)
        cntw[(size_t)team * CWORDS + i] = h[i];
}

// Per-node exclusive prefix over 256 team counts -> byte slot offsets;
// totals -> cnt_dense, c_src, c_dst; then prescale hs = x*c_src for the tile.
__global__ __launch_bounds__(1024) void offsets_prescale_kernel(
    const unsigned* __restrict__ cntw, unsigned* __restrict__ offsw,
    unsigned* __restrict__ cnt_dense, float* __restrict__ c_src,
    float* __restrict__ c_dst, const float2* __restrict__ x,
    unsigned* __restrict__ hs)
{
    __shared__ unsigned ldsC[128 * 64];   // counts tile [teamLocal][word]  32KB
    __shared__ unsigned ldsO[128 * 64];   // offset bytes [teamLocal][node] 32KB
    int tid = threadIdx.x;
    int n0 = blockIdx.x * 256;
    int w0 = n0 >> 2;
    int nl = tid >> 2;          // node-local 0..255
    int qq = tid & 3;           // quarter 0..3
    int myw = nl >> 2, myb = 8 * (nl & 3);
    unsigned carry = 0;         // full in-prefix for node nl
    unsigned od_part = 0;       // per-thread out-degree partial

    for (int ph = 0; ph < 2; ++ph) {
        int t0 = ph * 128;
        for (int i = tid; i < 128 * 64; i += 1024) {
            int tl = i >> 6, wl = i & 63;
            int gw = w0 + wl;
            ldsC[i] = (gw < CWORDS) ? cntw[(size_t)(t0 + tl) * CWORDS + gw] : 0u;
        }
        __syncthreads();
        unsigned lin = 0;
        unsigned char* ob = (unsigned char*)ldsO;
        int tl0 = qq * 32;
        for (int i = 0; i < 32; ++i) {
            int tl = tl0 + i;
            unsigned b = (ldsC[tl * 64 + myw] >> myb) & 255u;
            ob[tl * 256 + nl] = (unsigned char)lin;
            lin += (b & 15u);
            od_part += (b >> 4);
        }
        unsigned v1 = __shfl_up(lin, 1, 4);
        unsigned v2 = __shfl_up(lin, 2, 4);
        unsigned v3 = __shfl_up(lin, 3, 4);
        unsigned ein = (qq >= 1 ? v1 : 0u) + (qq >= 2 ? v2 : 0u) + (qq >= 3 ? v3 : 0u);
        unsigned base = carry + ein;
        for (int i = 0; i < 32; ++i) {
            int tl = tl0 + i;
            ob[tl * 256 + nl] = (unsigned char)(ob[tl * 256 + nl] + base);
        }
        carry += __shfl(ein + lin, 3, 4);   // phase total (q=3 inclusive)
        __syncthreads();
        for (int i = tid; i < 128 * 64; i += 1024) {
            int tl = i >> 6, wl = i & 63;
            int gw = w0 + wl;
            if (gw < CWORDS) offsw[(size_t)(t0 + tl) * CWORDS + gw] = ldsO[i];
        }
        __syncthreads();
    }
    float* ldsCs = (float*)ldsC;
    unsigned od = od_part;
    od += __shfl_xor(od, 1, 4);
    od += __shfl_xor(od, 2, 4);
    if (qq == 0) {
        int n = n0 + nl;
        unsigned id_ = carry;
        unsigned idc = id_ < 1u ? 1u : id_;
        unsigned odc = od < 1u ? 1u : od;
        float cs = 1.0f / sqrtf((float)odc);
        if (n < N_NODES) {
            cnt_dense[n] = id_ > 64u ? 64u : id_;
            c_dst[n] = 1.0f / sqrtf((float)idc);
            c_src[n] = cs;
        }
        ldsCs[nl] = cs;
    }
    __syncthreads();
    for (int i = tid; i < 256 * 64; i += 1024) {
        int row = i >> 6, col = i & 63;
        int n = n0 + row;
        if (n >= N_NODES) break;
        float c = ldsCs[row];
        float2 v = x[(size_t)n * 64 + col];
        hs[(size_t)n * 64 + col] = f2bf(v.x * c) | (f2bf(v.y * c) << 16);
    }
}

// Rescan slice, LDS position counters give unique local pos; write src
// directly into dense CSR at offs(team,d)+pos.
__global__ __launch_bounds__(1024) void scatter_kernel(
    const int* __restrict__ ei, const unsigned* __restrict__ offsw,
    unsigned* __restrict__ colc)
{
    __shared__ unsigned h[CWORDS];      // 50 KB pos counters (low nibble)
    int team = blockIdx.x, tid = threadIdx.x;
    for (int i = tid; i < CWORDS; i += 1024) h[i] = 0;
    __syncthreads();
    const unsigned char* __restrict__ ob =
        (const unsigned char*)offsw + (size_t)team * 50000;
    const int e0 = team * ESLICE;
    const int* __restrict__ srcp = ei;
    const int* __restrict__ dstp = ei + N_EDGES;
    for (int e = e0 + tid; e < e0 + ESLICE; e += 1024) {
        int s = srcp[e], d = dstp[e];
        unsigned old = atomicAdd(&h[d >> 2], 1u << (8 * (d & 3)));
        unsigned pos = (old >> (8 * (d & 3))) & 15u;
        unsigned slot = (unsigned)ob[d] + pos;
        if (slot < 64u) colc[(size_t)d * 64 + slot] = (unsigned)s;
    }
}

// m[n] = sum over in-edges of hs[src]. One wave per node; four 16-lane groups
// gather FOUR different edges' rows per uint4 load (1 KB per instruction).
__global__ __launch_bounds__(256) void aggregate_kernel(
    const unsigned* __restrict__ hs, const unsigned* __restrict__ colc,
    const unsigned* __restrict__ cnt_dense, unsigned* __restrict__ m,
    int total_waves)
{
    int wid  = (blockIdx.x * blockDim.x + threadIdx.x) >> 6;
    int lane = threadIdx.x & 63;
    int g = lane >> 4;             // edge-group 0..3
    int t = lane & 15;             // 16B chunk within row: uints 4t..4t+3
    for (int n = wid; n < N_NODES; n += total_waves) {
        unsigned deg = cnt_dense[n];
        unsigned myidx = colc[(size_t)n * 64 + lane];   // coalesced 256B
        float f0 = 0.f, f1 = 0.f, f2 = 0.f, f3 = 0.f;
        float f4 = 0.f, f5 = 0.f, f6 = 0.f, f7 = 0.f;
        for (unsigned j = 0; j < deg; j += 4) {
            unsigned e = j + g;
            unsigned s = (unsigned)__shfl((int)myidx, (int)e);
            bool v = e < deg;
            s = v ? s : 0u;
            uint4 u = *(const uint4*)(hs + (size_t)s * 64 + t * 4);
            if (!v) { u.x = 0u; u.y = 0u; u.z = 0u; u.w = 0u; }
            f0 += bf_lo(u.x); f1 += bf_hi(u.x);
            f2 += bf_lo(u.y); f3 += bf_hi(u.y);
            f4 += bf_lo(u.z); f5 += bf_hi(u.z);
            f6 += bf_lo(u.w); f7 += bf_hi(u.w);
        }
        f0 += __shfl_xor(f0, 16); f1 += __shfl_xor(f1, 16);
        f2 += __shfl_xor(f2, 16); f3 += __shfl_xor(f3, 16);
        f4 += __shfl_xor(f4, 16); f5 += __shfl_xor(f5, 16);
        f6 += __shfl_xor(f6, 16); f7 += __shfl_xor(f7, 16);
        f0 += __shfl_xor(f0, 32); f1 += __shfl_xor(f1, 32);
        f2 += __shfl_xor(f2, 32); f3 += __shfl_xor(f3, 32);
        f4 += __shfl_xor(f4, 32); f5 += __shfl_xor(f5, 32);
        f6 += __shfl_xor(f6, 32); f7 += __shfl_xor(f7, 32);
        if (g == 0) {
            uint4 r;
            r.x = f2bf(f0) | (f2bf(f1) << 16);
            r.y = f2bf(f2) | (f2bf(f3) << 16);
            r.z = f2bf(f4) | (f2bf(f5) << 16);
            r.w = f2bf(f6) | (f2bf(f7) << 16);
            *(uint4*)(m + (size_t)n * 64 + t * 4) = r;
        }
    }
}

// Hout = relu(c_dst[r]*(M@W) + b) [* c_src[r] if !last], MFMA 16x16x32 bf16.
__global__ __launch_bounds__(256) void mfma_gemm_kernel(
    const uint4* __restrict__ Mb, const uint4* __restrict__ Wf,
    const float* __restrict__ bias, const float* __restrict__ c_dst,
    const float* __restrict__ c_src, unsigned short* __restrict__ out_bf,
    float* __restrict__ out_f32, int last)
{
    int tid = threadIdx.x;
    int wave = tid >> 6, lane = tid & 63;
    int quad = lane >> 4, m16 = lane & 15;
    int r0 = blockIdx.x * 64 + wave * 16;

    int rA = r0 + m16; if (rA >= N_NODES) rA = N_NODES - 1;
    const uint4* pA = Mb + (size_t)rA * 16 + quad;
    union U { uint4 u; short8 s; };
    U a[4];
#pragma unroll
    for (int s = 0; s < 4; ++s) a[s].u = pA[s * 4];

    floatx4 acc[8];
#pragma unroll
    for (int c = 0; c < 8; ++c) {
        floatx4 ac = {0.f, 0.f, 0.f, 0.f};
#pragma unroll
        for (int s = 0; s < 4; ++s) {
            U b; b.u = Wf[(c * 4 + s) * 64 + lane];
            ac = __builtin_amdgcn_mfma_f32_16x16x32_bf16(a[s].s, b.s, ac, 0, 0, 0);
        }
        acc[c] = ac;
    }

    float cd[4], cs[4];
    int rows[4];
#pragma unroll
    for (int r = 0; r < 4; ++r) {
        int row = r0 + quad * 4 + r; rows[r] = row;
        bool ok = row < N_NODES;
        cd[r] = ok ? c_dst[row] : 0.f;
        cs[r] = (ok && !last) ? c_src[row] : 1.f;
    }
#pragma unroll
    for (int c = 0; c < 8; ++c) {
        int colg = c * 16 + m16;
        float b = bias[colg];
#pragma unroll
        for (int r = 0; r < 4; ++r) {
            int row = rows[r];
            if (row >= N_NODES) continue;
            float v = acc[c][r] * cd[r] + b;
            v = v > 0.f ? v : 0.f;
            if (last) out_f32[(size_t)row * DIM + colg] = v;
            else      out_bf[(size_t)row * DIM + colg] = (unsigned short)f2bf(v * cs[r]);
        }
    }
}

// Mean-pool readout on sorted graph_ids (fp32 h). Run-length local
// accumulate, one atomic per (graph-run, feature).
__global__ __launch_bounds__(128) void readout_kernel(
    const float* __restrict__ h, const int* __restrict__ gid,
    float* __restrict__ hg, float* __restrict__ cntg)
{
    int j  = threadIdx.x;
    int n0 = blockIdx.x * 64;
    float acc = 0.f; int cur = -1; int run = 0;
    for (int i = 0; i < 64; ++i) {
        int n = n0 + i;
        if (n >= N_NODES) break;
        int g = gid[n];
        if (g != cur) {
            if (cur >= 0) {
                atomicAdd(&hg[cur * DIM + j], acc);
                if (j == 0) atomicAdd(&cntg[cur], (float)run);
            }
            cur = g; acc = 0.f; run = 0;
        }
        acc += h[(size_t)n * DIM + j];
        run++;
    }
    if (cur >= 0) {
        atomicAdd(&hg[cur * DIM + j], acc);
        if (j == 0) atomicAdd(&cntg[cur], (float)run);
    }
}

__global__ __launch_bounds__(256) void head_kernel(
    const float* __restrict__ hg, const float* __restrict__ cntg,
    const float* __restrict__ Wc, const float* __restrict__ bc,
    float* __restrict__ out)
{
    int idx = blockIdx.x * blockDim.x + threadIdx.x;
    if (idx >= NGRAPH * NCLASS) return;
    int g = idx / NCLASS, c = idx % NCLASS;
    float inv = 1.0f / fmaxf(cntg[g], 1.0f);
    float s = 0.f;
    for (int j = 0; j < DIM; ++j) s = fmaf(hg[g * DIM + j], Wc[j * NCLASS + c], s);
    out[idx] = s * inv + bc[c];
}

// ---------------------------------------------------------------------------
extern "C" void kernel_launch(void* const* d_in, const int* in_sizes, int n_in,
                              void* d_out, int out_size, void* d_ws, size_t ws_size,
                              hipStream_t stream)
{
    const float* x   = (const float*)d_in[0];
    const float* W0  = (const float*)d_in[1];
    const float* b0  = (const float*)d_in[2];
    const float* Ws  = (const float*)d_in[3];
    const float* bs  = (const float*)d_in[4];
    const float* Wc  = (const float*)d_in[5];
    const float* bc  = (const float*)d_in[6];
    const int*   ei  = (const int*)d_in[7];
    const int*   gid = (const int*)d_in[8];
    float* out = (float*)d_out;

    char* ws = (char*)d_ws;
    size_t o = 0;
    auto alloc = [&](size_t bytes) {
        size_t r = o; o = (o + bytes + 255) & ~(size_t)255; return r;
    };
    unsigned* cntw      = (unsigned*)(ws + alloc((size_t)TEAMS * CWORDS * 4));
    unsigned* offsw     = (unsigned*)(ws + alloc((size_t)TEAMS * CWORDS * 4));
    unsigned* cnt_dense = (unsigned*)(ws + alloc((size_t)N_NODES * 4));
    float*    c_src     = (float*)(ws + alloc((size_t)N_NODES * 4));
    float*    c_dst     = (float*)(ws + alloc((size_t)N_NODES * 4));
    unsigned* colc      = (unsigned*)(ws + alloc((size_t)N_NODES * 64 * 4));
    unsigned* hs        = (unsigned*)(ws + alloc((size_t)N_NODES * 64 * 4));
    unsigned* mbuf      = (unsigned*)(ws + alloc((size_t)N_NODES * 64 * 4));
    float*    hlast     = (float*)(ws + alloc((size_t)N_NODES * DIM * 4));
    uint4*    Wf        = (uint4*)(ws + alloc((size_t)NLAYER * 2048 * 16));
    float*    hg        = (float*)(ws + alloc((size_t)NGRAPH * DIM * 4));
    float*    cntg      = (float*)(ws + alloc((size_t)NGRAPH * 4));

    count_wprep_kernel<<<TEAMS + 9, 1024, 0, stream>>>(ei, cntw, W0, Ws, Wf, hg, cntg);
    offsets_prescale_kernel<<<(N_NODES + 255) / 256, 1024, 0, stream>>>(
        cntw, offsw, cnt_dense, c_src, c_dst, (const float2*)x, hs);
    scatter_kernel<<<TEAMS, 1024, 0, stream>>>(ei, offsw, colc);

    const int AGG_BLOCKS = 2048;
    const int TOTAL_WAVES = AGG_BLOCKS * 4;
    const int GEMM_BLOCKS = (N_NODES + 63) / 64;

    for (int l = 0; l < NLAYER; ++l) {
        const float* b = (l == 0) ? b0 : (bs + (size_t)(l - 1) * DIM);
        int last = (l == NLAYER - 1) ? 1 : 0;
        aggregate_kernel<<<AGG_BLOCKS, 256, 0, stream>>>(
            hs, colc, cnt_dense, mbuf, TOTAL_WAVES);
        mfma_gemm_kernel<<<GEMM_BLOCKS, 256, 0, stream>>>(
            (const uint4*)mbuf, Wf + (size_t)l * 2048, b, c_dst, c_src,
            (unsigned short*)hs, hlast, last);
    }

    readout_kernel<<<(N_NODES + 63) / 64, 128, 0, stream>>>(hlast, gid, hg, cntg);
    head_kernel<<<(NGRAPH * NCLASS + 255) / 256, 256, 0, stream>>>(hg, cntg, Wc, bc, out);
}